// Round 2
// baseline (1489.036 us; speedup 1.0000x reference)
//
#include <hip/hip_runtime.h>

// TensorProductConv: Z[rows[e]] += msg(X[cols[e]], Y[e], W[e]),  msg is 352 f32.
// Inputs: X (N,128) f32, Y (E,4) f32, W (E,160) f32, rows (E) int32, cols (E) int32
// (harness passes integer inputs as int32 — jnp.int64 is downcast without x64 mode)
// Output: Z (N, 352) f32.

#define SQRT3_INV 0.57735026918962576451f
#define SQRT2_INV 0.70710678118654752440f

__global__ __launch_bounds__(256) void tpc_edge_kernel(
    const float* __restrict__ X,
    const float* __restrict__ Y,
    const float* __restrict__ W,
    const int* __restrict__ rows,
    const int* __restrict__ cols,
    float* __restrict__ Z,
    int n_edges)
{
    int gid = blockIdx.x * blockDim.x + threadIdx.x;
    int e = gid >> 5;        // 32 threads per edge, one per channel u
    int u = gid & 31;
    if (e >= n_edges) return;

    const int r = rows[e];
    const int c = cols[e];

    // Xj = X[c]: x0 = Xj[0:32], x1 = Xj[32:128].reshape(32,3)
    const float* Xr = X + (size_t)c * 128;
    const float x0  = Xr[u];
    const float x1a = Xr[32 + 3 * u + 0];
    const float x1b = Xr[32 + 3 * u + 1];
    const float x1c = Xr[32 + 3 * u + 2];

    const float y0  = Y[(size_t)e * 4 + 0];
    const float y1a = Y[(size_t)e * 4 + 1];
    const float y1b = Y[(size_t)e * 4 + 2];
    const float y1c = Y[(size_t)e * 4 + 3];

    // W[e] viewed as (5, 32)
    const float* We = W + (size_t)e * 160;
    const float w0 = We[u];
    const float w1 = We[32 + u];
    const float w2 = We[64 + u];
    const float w3 = We[96 + u];
    const float w4 = We[128 + u];

    // p1 = w0 * x0 * y0
    const float p1 = w0 * x0 * y0;
    // p2 = (w1 * x0) outer y1
    const float w1x0 = w1 * x0;
    const float p2a = w1x0 * y1a;
    const float p2b = w1x0 * y1b;
    const float p2c = w1x0 * y1c;
    // p3 = w2 * x1 * y0
    const float w2y0 = w2 * y0;
    const float p3a = w2y0 * x1a;
    const float p3b = w2y0 * x1b;
    const float p3c = w2y0 * x1c;
    // p4 = w3 * dot(x1, y1) / sqrt(3)
    const float dot = x1a * y1a + x1b * y1b + x1c * y1c;
    const float p4  = w3 * dot * SQRT3_INV;
    // p5 = w4 * cross(x1, y1) / sqrt(2)
    const float w4s = w4 * SQRT2_INV;
    const float p5a = w4s * (x1b * y1c - x1c * y1b);
    const float p5b = w4s * (x1c * y1a - x1a * y1c);
    const float p5c = w4s * (x1a * y1b - x1b * y1a);

    float* Zr = Z + (size_t)r * 352;
    atomicAdd(&Zr[u],              p1);
    atomicAdd(&Zr[32  + 3*u + 0],  p2a);
    atomicAdd(&Zr[32  + 3*u + 1],  p2b);
    atomicAdd(&Zr[32  + 3*u + 2],  p2c);
    atomicAdd(&Zr[128 + 3*u + 0],  p3a);
    atomicAdd(&Zr[128 + 3*u + 1],  p3b);
    atomicAdd(&Zr[128 + 3*u + 2],  p3c);
    atomicAdd(&Zr[224 + u],        p4);
    atomicAdd(&Zr[256 + 3*u + 0],  p5a);
    atomicAdd(&Zr[256 + 3*u + 1],  p5b);
    atomicAdd(&Zr[256 + 3*u + 2],  p5c);
}

extern "C" void kernel_launch(void* const* d_in, const int* in_sizes, int n_in,
                              void* d_out, int out_size, void* d_ws, size_t ws_size,
                              hipStream_t stream) {
    const float* X    = (const float*)d_in[0];
    const float* Y    = (const float*)d_in[1];
    const float* W    = (const float*)d_in[2];
    const int*   rows = (const int*)d_in[3];
    const int*   cols = (const int*)d_in[4];
    float* Z = (float*)d_out;

    const int n_edges = in_sizes[3];   // 500000

    // Harness poisons d_out once (0xAA) and never re-poisons between replays:
    // we must zero the accumulator every call.
    hipMemsetAsync(d_out, 0, (size_t)out_size * sizeof(float), stream);

    const long long threads_total = (long long)n_edges * 32;  // one thread per (edge, u)
    const int block = 256;
    const int grid  = (int)((threads_total + block - 1) / block);
    tpc_edge_kernel<<<grid, block, 0, stream>>>(X, Y, W, rows, cols, Z, n_edges);
}

// Round 3
// 178.959 us; speedup vs baseline: 8.3206x; 8.3206x over previous
//
#include <hip/hip_runtime.h>

// TensorProductConv: Z[rows[e]] += msg(X[cols[e]], Y[e], W[e]),  msg is 352 f32.
// Inputs: X (N,128) f32, Y (E,4) f32, W (E,160) f32, rows (E) int32, cols (E) int32
// Output: Z (N, 352) f32.
//
// Strategy: build CSR by destination node in d_ws every call (deterministic work),
// then one wave (64 lanes) per node gathers+accumulates its edges in registers and
// writes Z once — no atomics on the output.

#define SQRT3_INV 0.57735026918962576451f
#define SQRT2_INV 0.70710678118654752440f

#define SCAN_CHUNK 512

// ---------- CSR build ----------
__global__ void hist_kernel(const int* __restrict__ rows, int* __restrict__ deg, int nE) {
    int e = blockIdx.x * blockDim.x + threadIdx.x;
    if (e < nE) atomicAdd(&deg[rows[e]], 1);
}

__global__ void scan_phaseA(const int* __restrict__ deg, int* __restrict__ chunkSums, int n) {
    __shared__ int s[SCAN_CHUNK];
    int t = threadIdx.x;
    int i = blockIdx.x * SCAN_CHUNK + t;
    s[t] = (i < n) ? deg[i] : 0;
    __syncthreads();
    for (int st = SCAN_CHUNK / 2; st > 0; st >>= 1) {
        if (t < st) s[t] += s[t + st];
        __syncthreads();
    }
    if (t == 0) chunkSums[blockIdx.x] = s[0];
}

__global__ void scan_phaseB(const int* __restrict__ chunkSums, int* __restrict__ chunkOffs, int nchunks) {
    __shared__ int s[SCAN_CHUNK];
    int t = threadIdx.x;
    int v0 = (t < nchunks) ? chunkSums[t] : 0;
    s[t] = v0;
    __syncthreads();
    for (int st = 1; st < SCAN_CHUNK; st <<= 1) {
        int v = (t >= st) ? s[t - st] : 0;
        __syncthreads();
        s[t] += v;
        __syncthreads();
    }
    if (t < nchunks) chunkOffs[t] = s[t] - v0;   // exclusive scan of chunk sums
}

__global__ void scan_phaseC(const int* __restrict__ deg, const int* __restrict__ chunkOffs,
                            int* __restrict__ off, int* __restrict__ cur, int n) {
    __shared__ int s[SCAN_CHUNK];
    int t = threadIdx.x;
    int i = blockIdx.x * SCAN_CHUNK + t;
    int d = (i < n) ? deg[i] : 0;
    s[t] = d;
    __syncthreads();
    for (int st = 1; st < SCAN_CHUNK; st <<= 1) {
        int v = (t >= st) ? s[t - st] : 0;
        __syncthreads();
        s[t] += v;
        __syncthreads();
    }
    int excl = s[t] - d + chunkOffs[blockIdx.x];
    if (i < n) { off[i] = excl; cur[i] = excl; }
    if (i == n - 1) off[n] = excl + d;
}

__global__ void scatter_kernel(const int* __restrict__ rows, int* __restrict__ cur,
                               int* __restrict__ eidx, int nE) {
    int e = blockIdx.x * blockDim.x + threadIdx.x;
    if (e >= nE) return;
    int p = atomicAdd(&cur[rows[e]], 1);
    eidx[p] = e;
}

// ---------- main gather: one wave per node ----------
__global__ __launch_bounds__(256) void tpc_gather(
    const float* __restrict__ X,
    const float* __restrict__ Y,
    const float* __restrict__ W,
    const int* __restrict__ cols,
    const int* __restrict__ off,
    const int* __restrict__ eidx,
    float* __restrict__ Z,
    int n_nodes)
{
    int node = blockIdx.x * 4 + (threadIdx.x >> 6);
    if (node >= n_nodes) return;
    int lane = threadIdx.x & 63;
    int u    = lane & 31;      // channel
    int slot = lane >> 5;      // which of 2 concurrent edges

    float a1 = 0.f, a2a = 0.f, a2b = 0.f, a2c = 0.f;
    float a3a = 0.f, a3b = 0.f, a3c = 0.f, a4 = 0.f;
    float a5a = 0.f, a5b = 0.f, a5c = 0.f;

    const int s_beg = off[node];
    const int s_end = off[node + 1];

    for (int i = s_beg + slot; i < s_end; i += 2) {
        const int e = eidx[i];
        const int c = cols[e];

        const float* Xr = X + (size_t)c * 128;
        const float x0  = Xr[u];
        const float x1a = Xr[32 + 3 * u + 0];
        const float x1b = Xr[32 + 3 * u + 1];
        const float x1c = Xr[32 + 3 * u + 2];

        const float* Ye = Y + (size_t)e * 4;
        const float y0  = Ye[0];
        const float y1a = Ye[1];
        const float y1b = Ye[2];
        const float y1c = Ye[3];

        const float* We = W + (size_t)e * 160;
        const float w0 = We[u];
        const float w1 = We[32 + u];
        const float w2 = We[64 + u];
        const float w3 = We[96 + u];
        const float w4 = We[128 + u];

        a1 += w0 * x0 * y0;
        const float w1x0 = w1 * x0;
        a2a += w1x0 * y1a; a2b += w1x0 * y1b; a2c += w1x0 * y1c;
        const float w2y0 = w2 * y0;
        a3a += w2y0 * x1a; a3b += w2y0 * x1b; a3c += w2y0 * x1c;
        const float dot = x1a * y1a + x1b * y1b + x1c * y1c;
        a4 += w3 * dot * SQRT3_INV;
        const float w4s = w4 * SQRT2_INV;
        a5a += w4s * (x1b * y1c - x1c * y1b);
        a5b += w4s * (x1c * y1a - x1a * y1c);
        a5c += w4s * (x1a * y1b - x1b * y1a);
    }

    // combine the two 32-lane halves (slot 0 += slot 1)
    a1  += __shfl_xor(a1, 32, 64);
    a2a += __shfl_xor(a2a, 32, 64);
    a2b += __shfl_xor(a2b, 32, 64);
    a2c += __shfl_xor(a2c, 32, 64);
    a3a += __shfl_xor(a3a, 32, 64);
    a3b += __shfl_xor(a3b, 32, 64);
    a3c += __shfl_xor(a3c, 32, 64);
    a4  += __shfl_xor(a4, 32, 64);
    a5a += __shfl_xor(a5a, 32, 64);
    a5b += __shfl_xor(a5b, 32, 64);
    a5c += __shfl_xor(a5c, 32, 64);

    if (slot == 0) {
        float* Zr = Z + (size_t)node * 352;
        Zr[u]               = a1;
        Zr[32  + 3 * u + 0] = a2a;
        Zr[32  + 3 * u + 1] = a2b;
        Zr[32  + 3 * u + 2] = a2c;
        Zr[128 + 3 * u + 0] = a3a;
        Zr[128 + 3 * u + 1] = a3b;
        Zr[128 + 3 * u + 2] = a3c;
        Zr[224 + u]         = a4;
        Zr[256 + 3 * u + 0] = a5a;
        Zr[256 + 3 * u + 1] = a5b;
        Zr[256 + 3 * u + 2] = a5c;
    }
}

// ---------- fallback (round-2 atomic version) if workspace is too small ----------
__global__ __launch_bounds__(256) void tpc_edge_kernel(
    const float* __restrict__ X, const float* __restrict__ Y, const float* __restrict__ W,
    const int* __restrict__ rows, const int* __restrict__ cols, float* __restrict__ Z, int n_edges)
{
    int gid = blockIdx.x * blockDim.x + threadIdx.x;
    int e = gid >> 5;
    int u = gid & 31;
    if (e >= n_edges) return;
    const int r = rows[e];
    const int c = cols[e];
    const float* Xr = X + (size_t)c * 128;
    const float x0 = Xr[u];
    const float x1a = Xr[32 + 3 * u], x1b = Xr[33 + 3 * u], x1c = Xr[34 + 3 * u];
    const float* Ye = Y + (size_t)e * 4;
    const float y0 = Ye[0], y1a = Ye[1], y1b = Ye[2], y1c = Ye[3];
    const float* We = W + (size_t)e * 160;
    const float w0 = We[u], w1 = We[32 + u], w2 = We[64 + u], w3 = We[96 + u], w4 = We[128 + u];
    const float p1 = w0 * x0 * y0;
    const float w1x0 = w1 * x0;
    const float w2y0 = w2 * y0;
    const float dot = x1a * y1a + x1b * y1b + x1c * y1c;
    const float w4s = w4 * SQRT2_INV;
    float* Zr = Z + (size_t)r * 352;
    atomicAdd(&Zr[u], p1);
    atomicAdd(&Zr[32 + 3 * u + 0], w1x0 * y1a);
    atomicAdd(&Zr[32 + 3 * u + 1], w1x0 * y1b);
    atomicAdd(&Zr[32 + 3 * u + 2], w1x0 * y1c);
    atomicAdd(&Zr[128 + 3 * u + 0], w2y0 * x1a);
    atomicAdd(&Zr[128 + 3 * u + 1], w2y0 * x1b);
    atomicAdd(&Zr[128 + 3 * u + 2], w2y0 * x1c);
    atomicAdd(&Zr[224 + u], w3 * dot * SQRT3_INV);
    atomicAdd(&Zr[256 + 3 * u + 0], w4s * (x1b * y1c - x1c * y1b));
    atomicAdd(&Zr[256 + 3 * u + 1], w4s * (x1c * y1a - x1a * y1c));
    atomicAdd(&Zr[256 + 3 * u + 2], w4s * (x1a * y1b - x1b * y1a));
}

extern "C" void kernel_launch(void* const* d_in, const int* in_sizes, int n_in,
                              void* d_out, int out_size, void* d_ws, size_t ws_size,
                              hipStream_t stream) {
    const float* X    = (const float*)d_in[0];
    const float* Y    = (const float*)d_in[1];
    const float* W    = (const float*)d_in[2];
    const int*   rows = (const int*)d_in[3];
    const int*   cols = (const int*)d_in[4];
    float* Z = (float*)d_out;

    const int n_edges = in_sizes[3];
    const int n_nodes = in_sizes[0] / 128;
    const int nchunks = (n_nodes + SCAN_CHUNK - 1) / SCAN_CHUNK;

    // workspace layout (ints)
    size_t need = (size_t)(n_nodes + 1 + n_nodes + n_nodes + 2 * nchunks + n_edges) * sizeof(int);
    if (ws_size < need || nchunks > SCAN_CHUNK) {
        // fallback: atomic scatter version
        hipMemsetAsync(d_out, 0, (size_t)out_size * sizeof(float), stream);
        const long long threads_total = (long long)n_edges * 32;
        const int grid = (int)((threads_total + 255) / 256);
        tpc_edge_kernel<<<grid, 256, 0, stream>>>(X, Y, W, rows, cols, Z, n_edges);
        return;
    }

    int* p = (int*)d_ws;
    int* off       = p;                 p += n_nodes + 1;
    int* cur       = p;                 p += n_nodes;
    int* deg       = p;                 p += n_nodes;
    int* chunkSums = p;                 p += nchunks;
    int* chunkOffs = p;                 p += nchunks;
    int* eidx      = p;

    hipMemsetAsync(deg, 0, (size_t)n_nodes * sizeof(int), stream);

    const int gE = (n_edges + 255) / 256;
    hist_kernel<<<gE, 256, 0, stream>>>(rows, deg, n_edges);
    scan_phaseA<<<nchunks, SCAN_CHUNK, 0, stream>>>(deg, chunkSums, n_nodes);
    scan_phaseB<<<1, SCAN_CHUNK, 0, stream>>>(chunkSums, chunkOffs, nchunks);
    scan_phaseC<<<nchunks, SCAN_CHUNK, 0, stream>>>(deg, chunkOffs, off, cur, n_nodes);
    scatter_kernel<<<gE, 256, 0, stream>>>(rows, cur, eidx, n_edges);

    // main gather: 4 waves per block, one wave per node
    const int gN = (n_nodes + 3) / 4;
    tpc_gather<<<gN, 256, 0, stream>>>(X, Y, W, cols, off, eidx, Z, n_nodes);
}

// Round 4
// 176.519 us; speedup vs baseline: 8.4355x; 1.0138x over previous
//
#include <hip/hip_runtime.h>

// TensorProductConv: Z[rows[e]] += msg(X[cols[e]], Y[e], W[e]),  msg is 352 f32.
// Inputs: X (N,128) f32, Y (E,4) f32, W (E,160) f32, rows (E) int32, cols (E) int32
// Output: Z (N, 352) f32.
//
// CSR build in d_ws each call, then one 32-lane half-wave per destination node
// gathers+accumulates its edges in registers (loop unrolled x2 for MLP) and
// writes Z once. Stream-once data (W, Y, eidx, cols) uses nontemporal loads to
// keep L2/L3 capacity for the reused X table.

#define SQRT3_INV 0.57735026918962576451f
#define SQRT2_INV 0.70710678118654752440f

#define SCAN_CHUNK 512

// ---------- CSR build ----------
__global__ void zero_kernel(int* __restrict__ p, int n) {
    int i = blockIdx.x * blockDim.x + threadIdx.x;
    if (i < n) p[i] = 0;
}

__global__ void hist_kernel(const int* __restrict__ rows, int* __restrict__ deg, int nE) {
    int e = blockIdx.x * blockDim.x + threadIdx.x;
    if (e < nE) atomicAdd(&deg[rows[e]], 1);
}

__global__ void scan_phaseA(const int* __restrict__ deg, int* __restrict__ chunkSums, int n) {
    __shared__ int s[SCAN_CHUNK];
    int t = threadIdx.x;
    int i = blockIdx.x * SCAN_CHUNK + t;
    s[t] = (i < n) ? deg[i] : 0;
    __syncthreads();
    for (int st = SCAN_CHUNK / 2; st > 0; st >>= 1) {
        if (t < st) s[t] += s[t + st];
        __syncthreads();
    }
    if (t == 0) chunkSums[blockIdx.x] = s[0];
}

__global__ void scan_phaseB(const int* __restrict__ chunkSums, int* __restrict__ chunkOffs, int nchunks) {
    __shared__ int s[SCAN_CHUNK];
    int t = threadIdx.x;
    int v0 = (t < nchunks) ? chunkSums[t] : 0;
    s[t] = v0;
    __syncthreads();
    for (int st = 1; st < SCAN_CHUNK; st <<= 1) {
        int v = (t >= st) ? s[t - st] : 0;
        __syncthreads();
        s[t] += v;
        __syncthreads();
    }
    if (t < nchunks) chunkOffs[t] = s[t] - v0;   // exclusive scan of chunk sums
}

__global__ void scan_phaseC(const int* __restrict__ deg, const int* __restrict__ chunkOffs,
                            int* __restrict__ off, int* __restrict__ cur, int n) {
    __shared__ int s[SCAN_CHUNK];
    int t = threadIdx.x;
    int i = blockIdx.x * SCAN_CHUNK + t;
    int d = (i < n) ? deg[i] : 0;
    s[t] = d;
    __syncthreads();
    for (int st = 1; st < SCAN_CHUNK; st <<= 1) {
        int v = (t >= st) ? s[t - st] : 0;
        __syncthreads();
        s[t] += v;
        __syncthreads();
    }
    int excl = s[t] - d + chunkOffs[blockIdx.x];
    if (i < n) { off[i] = excl; cur[i] = excl; }
    if (i == n - 1) off[n] = excl + d;
}

__global__ void scatter_kernel(const int* __restrict__ rows, int* __restrict__ cur,
                               int* __restrict__ eidx, int nE) {
    int e = blockIdx.x * blockDim.x + threadIdx.x;
    if (e >= nE) return;
    int p = atomicAdd(&cur[rows[e]], 1);
    eidx[p] = e;
}

// ---------- main gather: one node per 32-lane half-wave ----------
__global__ __launch_bounds__(256) void tpc_gather(
    const float* __restrict__ X,
    const float* __restrict__ Y,
    const float* __restrict__ W,
    const int* __restrict__ cols,
    const int* __restrict__ off,
    const int* __restrict__ eidx,
    float* __restrict__ Z,
    int n_nodes)
{
    int node = blockIdx.x * 8 + (threadIdx.x >> 5);   // 8 half-waves per 256-thr block
    if (node >= n_nodes) return;
    int u = threadIdx.x & 31;

    float a1 = 0.f, a2a = 0.f, a2b = 0.f, a2c = 0.f;
    float a3a = 0.f, a3b = 0.f, a3c = 0.f, a4 = 0.f;
    float a5a = 0.f, a5b = 0.f, a5c = 0.f;

    const int beg = off[node];
    const int end = off[node + 1];

#define EDGE_BODY(E_, C_)                                                     \
    do {                                                                      \
        const float* Xr = X + (size_t)(C_) * 128;                             \
        const float x0  = Xr[u];                                              \
        const float x1a = Xr[32 + 3 * u + 0];                                 \
        const float x1b = Xr[32 + 3 * u + 1];                                 \
        const float x1c = Xr[32 + 3 * u + 2];                                 \
        const float* Ye = Y + (size_t)(E_) * 4;                               \
        const float y0  = __builtin_nontemporal_load(Ye + 0);                 \
        const float y1a = __builtin_nontemporal_load(Ye + 1);                 \
        const float y1b = __builtin_nontemporal_load(Ye + 2);                 \
        const float y1c = __builtin_nontemporal_load(Ye + 3);                 \
        const float* We = W + (size_t)(E_) * 160;                             \
        const float w0 = __builtin_nontemporal_load(We + u);                  \
        const float w1 = __builtin_nontemporal_load(We + 32 + u);             \
        const float w2 = __builtin_nontemporal_load(We + 64 + u);             \
        const float w3 = __builtin_nontemporal_load(We + 96 + u);             \
        const float w4 = __builtin_nontemporal_load(We + 128 + u);            \
        a1 += w0 * x0 * y0;                                                   \
        const float w1x0 = w1 * x0;                                           \
        a2a += w1x0 * y1a; a2b += w1x0 * y1b; a2c += w1x0 * y1c;              \
        const float w2y0 = w2 * y0;                                           \
        a3a += w2y0 * x1a; a3b += w2y0 * x1b; a3c += w2y0 * x1c;              \
        const float dot = x1a * y1a + x1b * y1b + x1c * y1c;                  \
        a4 += w3 * dot * SQRT3_INV;                                           \
        const float w4s = w4 * SQRT2_INV;                                     \
        a5a += w4s * (x1b * y1c - x1c * y1b);                                 \
        a5b += w4s * (x1c * y1a - x1a * y1c);                                 \
        a5c += w4s * (x1a * y1b - x1b * y1a);                                 \
    } while (0)

    int i = beg;
    for (; i + 1 < end; i += 2) {
        // two independent load chains in flight
        const int e0 = __builtin_nontemporal_load(eidx + i);
        const int e1 = __builtin_nontemporal_load(eidx + i + 1);
        const int c0 = __builtin_nontemporal_load(cols + e0);
        const int c1 = __builtin_nontemporal_load(cols + e1);
        EDGE_BODY(e0, c0);
        EDGE_BODY(e1, c1);
    }
    if (i < end) {
        const int e0 = __builtin_nontemporal_load(eidx + i);
        const int c0 = __builtin_nontemporal_load(cols + e0);
        EDGE_BODY(e0, c0);
    }
#undef EDGE_BODY

    float* Zr = Z + (size_t)node * 352;
    __builtin_nontemporal_store(a1,  Zr + u);
    __builtin_nontemporal_store(a2a, Zr + 32 + 3 * u + 0);
    __builtin_nontemporal_store(a2b, Zr + 32 + 3 * u + 1);
    __builtin_nontemporal_store(a2c, Zr + 32 + 3 * u + 2);
    __builtin_nontemporal_store(a3a, Zr + 128 + 3 * u + 0);
    __builtin_nontemporal_store(a3b, Zr + 128 + 3 * u + 1);
    __builtin_nontemporal_store(a3c, Zr + 128 + 3 * u + 2);
    __builtin_nontemporal_store(a4,  Zr + 224 + u);
    __builtin_nontemporal_store(a5a, Zr + 256 + 3 * u + 0);
    __builtin_nontemporal_store(a5b, Zr + 256 + 3 * u + 1);
    __builtin_nontemporal_store(a5c, Zr + 256 + 3 * u + 2);
}

// ---------- fallback (atomic version) if workspace is too small ----------
__global__ __launch_bounds__(256) void tpc_edge_kernel(
    const float* __restrict__ X, const float* __restrict__ Y, const float* __restrict__ W,
    const int* __restrict__ rows, const int* __restrict__ cols, float* __restrict__ Z, int n_edges)
{
    int gid = blockIdx.x * blockDim.x + threadIdx.x;
    int e = gid >> 5;
    int u = gid & 31;
    if (e >= n_edges) return;
    const int r = rows[e];
    const int c = cols[e];
    const float* Xr = X + (size_t)c * 128;
    const float x0 = Xr[u];
    const float x1a = Xr[32 + 3 * u], x1b = Xr[33 + 3 * u], x1c = Xr[34 + 3 * u];
    const float* Ye = Y + (size_t)e * 4;
    const float y0 = Ye[0], y1a = Ye[1], y1b = Ye[2], y1c = Ye[3];
    const float* We = W + (size_t)e * 160;
    const float w0 = We[u], w1 = We[32 + u], w2 = We[64 + u], w3 = We[96 + u], w4 = We[128 + u];
    const float p1 = w0 * x0 * y0;
    const float w1x0 = w1 * x0;
    const float w2y0 = w2 * y0;
    const float dot = x1a * y1a + x1b * y1b + x1c * y1c;
    const float w4s = w4 * SQRT2_INV;
    float* Zr = Z + (size_t)r * 352;
    atomicAdd(&Zr[u], p1);
    atomicAdd(&Zr[32 + 3 * u + 0], w1x0 * y1a);
    atomicAdd(&Zr[32 + 3 * u + 1], w1x0 * y1b);
    atomicAdd(&Zr[32 + 3 * u + 2], w1x0 * y1c);
    atomicAdd(&Zr[128 + 3 * u + 0], w2y0 * x1a);
    atomicAdd(&Zr[128 + 3 * u + 1], w2y0 * x1b);
    atomicAdd(&Zr[128 + 3 * u + 2], w2y0 * x1c);
    atomicAdd(&Zr[224 + u], w3 * dot * SQRT3_INV);
    atomicAdd(&Zr[256 + 3 * u + 0], w4s * (x1b * y1c - x1c * y1b));
    atomicAdd(&Zr[256 + 3 * u + 1], w4s * (x1c * y1a - x1a * y1c));
    atomicAdd(&Zr[256 + 3 * u + 2], w4s * (x1a * y1b - x1b * y1a));
}

extern "C" void kernel_launch(void* const* d_in, const int* in_sizes, int n_in,
                              void* d_out, int out_size, void* d_ws, size_t ws_size,
                              hipStream_t stream) {
    const float* X    = (const float*)d_in[0];
    const float* Y    = (const float*)d_in[1];
    const float* W    = (const float*)d_in[2];
    const int*   rows = (const int*)d_in[3];
    const int*   cols = (const int*)d_in[4];
    float* Z = (float*)d_out;

    const int n_edges = in_sizes[3];
    const int n_nodes = in_sizes[0] / 128;
    const int nchunks = (n_nodes + SCAN_CHUNK - 1) / SCAN_CHUNK;

    size_t need = (size_t)(n_nodes + 1 + n_nodes + n_nodes + 2 * nchunks + n_edges) * sizeof(int);
    if (ws_size < need || nchunks > SCAN_CHUNK) {
        hipMemsetAsync(d_out, 0, (size_t)out_size * sizeof(float), stream);
        const long long threads_total = (long long)n_edges * 32;
        const int grid = (int)((threads_total + 255) / 256);
        tpc_edge_kernel<<<grid, 256, 0, stream>>>(X, Y, W, rows, cols, Z, n_edges);
        return;
    }

    int* p = (int*)d_ws;
    int* off       = p;                 p += n_nodes + 1;
    int* cur       = p;                 p += n_nodes;
    int* deg       = p;                 p += n_nodes;
    int* chunkSums = p;                 p += nchunks;
    int* chunkOffs = p;                 p += nchunks;
    int* eidx      = p;

    const int gE = (n_edges + 255) / 256;
    const int gN = (n_nodes + 255) / 256;

    zero_kernel<<<gN, 256, 0, stream>>>(deg, n_nodes);
    hist_kernel<<<gE, 256, 0, stream>>>(rows, deg, n_edges);
    scan_phaseA<<<nchunks, SCAN_CHUNK, 0, stream>>>(deg, chunkSums, n_nodes);
    scan_phaseB<<<1, SCAN_CHUNK, 0, stream>>>(chunkSums, chunkOffs, nchunks);
    scan_phaseC<<<nchunks, SCAN_CHUNK, 0, stream>>>(deg, chunkOffs, off, cur, n_nodes);
    scatter_kernel<<<gE, 256, 0, stream>>>(rows, cur, eidx, n_edges);

    // main gather: one node per half-wave, 8 nodes per 256-thread block
    const int gG = (n_nodes + 7) / 8;
    tpc_gather<<<gG, 256, 0, stream>>>(X, Y, W, cols, off, eidx, Z, n_nodes);
}